// Round 22
// baseline (154.715 us; speedup 1.0000x reference)
//
#include <hip/hip_runtime.h>
#include <stdint.h>

// RoPE attention, MI355X. S=4096, HID=1024, 16 heads x 64.
// R22 = R21 + attn staging via global_load_lds with PRE-SWIZZLED K/V global
// layouts (rule #21: linear LDS dest + inverse-swizzled source + swizzled read).
// Gemm epilogue stores K/V as the swizzled LDS image laid out linearly
// (stored_byte = orig_byte ^ ((row&15)<<3), K row=key&31, V row=d&31); attn
// staging = 2 x gll16 (1KB) per wave per tile: no reg round-trip, no b64
// scatter writes (conflict source), reads byte-identical to proven R13/R21.
// ws layout: qbf 8MB | Kswz 8MB | Vswz 8MB | xbf 8MB | wbf 6MB | ctst 1MB

#define SEQLEN 4096
#define NHEAD 16
#define HDIM 64

typedef __bf16 bf16x8 __attribute__((ext_vector_type(8)));
typedef float f32x4 __attribute__((ext_vector_type(4)));
typedef float f32x16 __attribute__((ext_vector_type(16)));

__device__ __forceinline__ unsigned short f2bf(float f) {
  union { float f; unsigned int u; } v; v.f = f;
  unsigned int r = v.u + 0x7FFFu + ((v.u >> 16) & 1u);
  return (unsigned short)(r >> 16);
}
__device__ __forceinline__ unsigned int pkc(float lo, float hi) {
  union { __bf16 b[2]; unsigned int u; } z;
  z.b[0] = (__bf16)lo; z.b[1] = (__bf16)hi;
  return z.u;
}
__device__ __forceinline__ bf16x8 as_bf(uint4 v) { return __builtin_bit_cast(bf16x8, v); }
__device__ __forceinline__ f32x4 mfma16(bf16x8 a, bf16x8 b, f32x4 c) {
  return __builtin_amdgcn_mfma_f32_16x16x32_bf16(a, b, c, 0, 0, 0);
}
__device__ __forceinline__ f32x16 mfma32(bf16x8 a, bf16x8 b, f32x16 c) {
  return __builtin_amdgcn_mfma_f32_32x32x16_bf16(a, b, c, 0, 0, 0);
}
__device__ __forceinline__ void gll16(const void* g, void* l) {
  __builtin_amdgcn_global_load_lds(
      (const __attribute__((address_space(1))) void*)g,
      (__attribute__((address_space(3))) void*)l, 16, 0, 0);
}

// ---------------- prep: fp32->bf16 convert (x, wq|wk|wv) + RoPE float2 table ----
__global__ __launch_bounds__(256) void k_prep(
    const float* __restrict__ x, const float* __restrict__ wq,
    const float* __restrict__ wk, const float* __restrict__ wv,
    unsigned short* __restrict__ xbf, unsigned short* __restrict__ wbf,
    float2* __restrict__ ctst) {
  const int NX = SEQLEN * 1024 / 4;         // 1048576 float4s
  const int NW = 1024 * 1024 / 4;           // 262144 (pow2)
  if (blockIdx.x < 7168) {
    int i = blockIdx.x * 256 + threadIdx.x;
    float4 v;
    unsigned short* dst;
    int di;
    if (i < NX) {
      v = ((const float4*)x)[i]; dst = xbf; di = i;
    } else {
      int j = i - NX;
      const float4* src = (const float4*)((j < NW) ? wq : (j < 2 * NW) ? wk : wv);
      v = src[j & (NW - 1)];
      dst = wbf; di = j;
    }
    ushort4 o; o.x = f2bf(v.x); o.y = f2bf(v.y); o.z = f2bf(v.z); o.w = f2bf(v.w);
    ((ushort4*)dst)[di] = o;
  } else {
    int i = (blockIdx.x - 7168) * 256 + threadIdx.x;   // 4096*32 entries
    int s = i >> 5, j = i & 31;
    double inv = exp(-(double)j * 0.28782313662425572);  // ln(10000)/32
    double a = (double)s * inv;
    float2 cs; cs.x = (float)cos(a); cs.y = (float)sin(a);
    ctst[i] = cs;
  }
}

// ---------------- QKV GEMM (gll16 staging; K/V stored pre-swizzled) ----------------
__global__ __launch_bounds__(256) void k_gemm(
    const unsigned short* __restrict__ xbf, const unsigned short* __restrict__ wbf,
    const float2* __restrict__ ctst,
    unsigned short* __restrict__ qbf, unsigned short* __restrict__ Kswz,
    unsigned short* __restrict__ Vswz) {
  __shared__ __align__(16) unsigned short As[2][128 * 32];  // 8KB per buffer
  __shared__ __align__(16) unsigned short Bs[2][128 * 32];
  const int t = threadIdx.x;
  const int bn = blockIdx.x, bm = blockIdx.y;
  const int lane = t & 63, wave = t >> 6;
  const int r = lane & 15, g = lane >> 4;
  const int wm = wave >> 1, wn = wave & 1;

  const int c0 = 2 * wave, c1 = 2 * wave + 1;
  const int srowA = lane >> 2, sb = (lane & 3) * 16;
  const char* gA0 = (const char*)xbf + (size_t)(bm * 128 + 16 * c0 + srowA) * 2048 + sb;
  const char* gA1 = (const char*)xbf + (size_t)(bm * 128 + 16 * c1 + srowA) * 2048 + sb;
  const char* gB0 = (const char*)wbf + (size_t)(bn * 128 + 16 * c0 + srowA) * 2048 + sb;
  const char* gB1 = (const char*)wbf + (size_t)(bn * 128 + 16 * c1 + srowA) * 2048 + sb;

  gll16(gA0, (char*)As[0] + c0 * 1024);
  gll16(gA1, (char*)As[0] + c1 * 1024);
  gll16(gB0, (char*)Bs[0] + c0 * 1024);
  gll16(gB1, (char*)Bs[0] + c1 * 1024);
  gA0 += 64; gA1 += 64; gB0 += 64; gB1 += 64;

  f32x4 zero4 = {0.f, 0.f, 0.f, 0.f};
  f32x4 acc[4][4];
#pragma unroll
  for (int m = 0; m < 4; ++m)
#pragma unroll
    for (int n = 0; n < 4; ++n) acc[m][n] = zero4;

  for (int kk = 0; kk < 32; ++kk) {
    __syncthreads();
    if (kk < 31) {
      char* Ad = (char*)As[(kk + 1) & 1];
      char* Bd = (char*)Bs[(kk + 1) & 1];
      gll16(gA0, Ad + c0 * 1024);
      gll16(gA1, Ad + c1 * 1024);
      gll16(gB0, Bd + c0 * 1024);
      gll16(gB1, Bd + c1 * 1024);
      gA0 += 64; gA1 += 64; gB0 += 64; gB1 += 64;
    }
    const char* Ac = (const char*)As[kk & 1];
    const char* Bc = (const char*)Bs[kk & 1];
    bf16x8 af[4], bfr[4];
#pragma unroll
    for (int m = 0; m < 4; ++m)
      af[m] = as_bf(*(const uint4*)(Ac + (wm * 64 + m * 16 + r) * 64 + g * 16));
#pragma unroll
    for (int n = 0; n < 4; ++n)
      bfr[n] = as_bf(*(const uint4*)(Bc + (wn * 64 + n * 16 + r) * 64 + g * 16));
#pragma unroll
    for (int m = 0; m < 4; ++m)
#pragma unroll
      for (int n = 0; n < 4; ++n)
        acc[m][n] = mfma16(af[m], bfr[n], acc[m][n]);
  }

  // Epilogue. C/D layout: col = lane&15 (=r), row = 4*g + reg.
  const int matid = bn >> 3;  // 0=q, 1=k, 2=v
#pragma unroll
  for (int m = 0; m < 4; ++m) {
    const int row0 = bm * 128 + wm * 64 + m * 16 + 4 * g;
#pragma unroll
    for (int n = 0; n < 4; ++n) {
      const int col = bn * 128 + wn * 64 + n * 16 + r;
      const int d = col & 63;
      const int hh = (col >> 6) & 15;
      if (matid < 2) {
        const int jdx = (col >> 1) & 31;
        const float sgn = (col & 1) ? 1.0f : -1.0f;
        const float qs = (matid == 0) ? 0.18033688011112042f : 1.0f;
#pragma unroll
        for (int j = 0; j < 4; ++j) {
          float v = acc[m][n][j];
          float p = __shfl_xor(v, 1);  // RoPE pair partner (col^1)
          int key = row0 + j;
          float2 cs = ctst[key * 32 + jdx];
          float o = (v * cs.x + p * cs.y * sgn) * qs;
          if (matid == 0) {
            qbf[(size_t)key * 1024 + (hh * 64 + d)] = f2bf(o);
          } else {
            // Kswz[h][key][128B]: stored byte = (2d) ^ ((key&15)<<3)
            size_t off = (size_t)hh * 524288 + (size_t)key * 128 +
                         (size_t)((2 * d) ^ ((key & 15) << 3));
            *(unsigned short*)((char*)Kswz + off) = f2bf(o);
          }
        }
      } else {
        // Vswz[h][kt][d&31][128B]: b64 slot = ((d>>5)*8 + ((row0>>2)&7)) ^ (d&15)
        ushort4 o;
        o.x = f2bf(acc[m][n][0]); o.y = f2bf(acc[m][n][1]);
        o.z = f2bf(acc[m][n][2]); o.w = f2bf(acc[m][n][3]);
        size_t off = (size_t)hh * 524288 + (size_t)(row0 >> 5) * 4096 +
                     (size_t)(d & 31) * 128 +
                     (size_t)((((d >> 5) * 8 + ((row0 >> 2) & 7)) ^ (d & 15)) << 3);
        *(ushort4*)((char*)Vswz + off) = o;
      }
    }
  }
}

// ---------------- Flash attention (KVBLK=32; gll16 staging from pre-swizzled
//                  global; reads/softmax/PV byte-identical to R13/R21) ----------------
__global__ __launch_bounds__(512) void k_attn(
    const unsigned short* __restrict__ qbf, const unsigned short* __restrict__ Kswz,
    const unsigned short* __restrict__ Vswz, float* __restrict__ out) {
  __shared__ __align__(16) char smem[33280];  // 2 halves x (K0|K1|V0|V1 4KB) + combine
  const int t = threadIdx.x;
  // XCD swizzle: 512 blocks, 8 XCDs, 64 blocks/XCD -> 2 heads per XCD
  const int b = blockIdx.x;
  const int work = (b & 7) * 64 + (b >> 3);
  const int h = work >> 5;
  const int qb = work & 31;
  const int lane = t & 63, wave = t >> 6;
  const int qw = wave & 3, hf = wave >> 2;
  const int li = lane & 31, hi = lane >> 5;
  const int q0 = qb * 128 + qw * 32;
  const int HB = hf * 16384;   // this wave's LDS half

  // Q fragments (B-operand): lane holds q = q0+li, d = c*16 + hi*8 + j. Pre-scaled.
  bf16x8 qf[4];
#pragma unroll
  for (int c = 0; c < 4; ++c)
    qf[c] = as_bf(*(const uint4*)((const char*)qbf +
              (size_t)(q0 + li) * 2048 + h * 128 + c * 32 + hi * 16));

  f32x16 z16 = {0.f};
  f32x16 acc[2];            // O^T accum: d-tile dt, row=d, col=q
  acc[0] = z16; acc[1] = z16;
  float l4[4] = {0.f, 0.f, 0.f, 0.f};

  // ---- loop-invariant LDS read addresses (unchanged from R13/R21) ----
  const int mmK = (li & 15) ^ (hi << 1);
  int kra[4];
#pragma unroll
  for (int c = 0; c < 4; ++c)
    kra[c] = HB + li * 128 + ((((4 * c) ^ mmK)) << 3);
  const int mmV = (li & 15) ^ hi;
  int vra[2][2];
#pragma unroll
  for (int dt = 0; dt < 2; ++dt)
#pragma unroll
    for (int kc = 0; kc < 2; ++kc)
      vra[dt][kc] = HB + 8192 + li * 128 + ((((dt * 8 + 4 * kc) ^ mmV)) << 3);

  // ---- gll16 staging: wave qw stages 1KB of K and 1KB of V per tile ----
  const char* pK = (const char*)Kswz + (size_t)h * 524288 + (size_t)hf * 262144 +
                   (size_t)qw * 1024 + (size_t)lane * 16;
  const char* pV = (const char*)Vswz + (size_t)h * 524288 + (size_t)hf * 262144 +
                   (size_t)qw * 1024 + (size_t)lane * 16;
  char* dK = smem + HB + qw * 1024;          // wave-uniform LDS dests
  char* dV = smem + HB + 8192 + qw * 1024;

  // prologue: tile 0 -> buffer 0
  gll16(pK, dK);
  gll16(pV, dV);
  pK += 4096; pV += 4096;

  for (int j = 0; j < 64; ++j) {
    __syncthreads();   // tile-j staging complete; prior reads drained
    if (j < 63) {
      const int NB = ((j + 1) & 1) * 4096;
      gll16(pK, dK + NB);
      gll16(pV, dV + NB);
      pK += 4096; pV += 4096;
    }
    const int JB = (j & 1) * 4096;

    // ---- QK^T: S^T[key][q], one 32-key subtile ----
    f32x16 sT = z16;
    __builtin_amdgcn_s_setprio(1);
#pragma unroll
    for (int c = 0; c < 4; ++c) {
      uint2 a0 = *(const uint2*)(smem + (kra[c] + JB));
      uint2 a1 = *(const uint2*)(smem + ((kra[c] ^ 8) + JB));
      uint4 ku; ku.x = a0.x; ku.y = a0.y; ku.z = a1.x; ku.w = a1.y;
      sT = mfma32(as_bf(ku), qf[c], sT);
    }
    __builtin_amdgcn_s_setprio(0);

    // ---- V A-frags (sigma order) ----
    bf16x8 vf[2][2];
#pragma unroll
    for (int dt = 0; dt < 2; ++dt)
#pragma unroll
      for (int kc = 0; kc < 2; ++kc) {
        uint2 lo = *(const uint2*)(smem + (vra[dt][kc] + JB));
        uint2 hi2 = *(const uint2*)(smem + ((vra[dt][kc] ^ 16) + JB));
        uint4 vv; vv.x = lo.x; vv.y = lo.y; vv.z = hi2.x; vv.w = hi2.y;
        vf[dt][kc] = as_bf(vv);
      }

    // ---- p = exp2(raw score); bounded, no max needed ----
#pragma unroll
    for (int i = 0; i < 16; ++i) sT[i] = __builtin_amdgcn_exp2f(sT[i]);

    // ---- denominator partials (4 accumulators) ----
#pragma unroll
    for (int i = 0; i < 4; ++i)
      l4[i] += (sT[i] + sT[i + 4]) + (sT[i + 8] + sT[i + 12]);

    // ---- pack P B-frags, then 4-MFMA PV cluster ----
    bf16x8 pfr[2];
#pragma unroll
    for (int kc = 0; kc < 2; ++kc) {
      const int bix = kc * 8;
      uint4 bw;
      bw.x = pkc(sT[bix + 0], sT[bix + 1]);
      bw.y = pkc(sT[bix + 2], sT[bix + 3]);
      bw.z = pkc(sT[bix + 4], sT[bix + 5]);
      bw.w = pkc(sT[bix + 6], sT[bix + 7]);
      pfr[kc] = as_bf(bw);
    }
    __builtin_amdgcn_s_setprio(1);
#pragma unroll
    for (int kc = 0; kc < 2; ++kc) {
      acc[0] = mfma32(vf[0][kc], pfr[kc], acc[0]);
      acc[1] = mfma32(vf[1][kc], pfr[kc], acc[1]);
    }
    __builtin_amdgcn_s_setprio(0);
  }

  float lrun = (l4[0] + l4[1]) + (l4[2] + l4[3]);
  // per-half full denominator (own hi-half + partner)
  float lhalf = lrun + __shfl_xor(lrun, 32);

  // ---- flash-combine of the two KV halves via LDS (plain add; no max) ----
  __syncthreads();
  float* shm = (float*)smem;
  if (hf == 1) {
    float* ab = shm + qw * 2048;   // [64 d][32 q]
#pragma unroll
    for (int dt = 0; dt < 2; ++dt)
#pragma unroll
      for (int i = 0; i < 16; ++i) {
        int d = (i & 3) + 8 * (i >> 2) + 4 * hi + 32 * dt;
        ab[d * 32 + li] = acc[dt][i];
      }
    if (hi == 0) shm[8192 + qw * 32 + li] = lhalf;
  }
  __syncthreads();
  if (hf == 0) {
    float* ab = shm + qw * 2048;
    float l1 = shm[8192 + qw * 32 + li];
    float linv = 1.0f / (lhalf + l1);
#pragma unroll
    for (int dt = 0; dt < 2; ++dt)
#pragma unroll
      for (int i = 0; i < 16; ++i) {
        int d = (i & 3) + 8 * (i >> 2) + 4 * hi + 32 * dt;
        acc[dt][i] = (acc[dt][i] + ab[d * 32 + li]) * linv;
      }
    __asm__ volatile("" ::: "memory");

    // ---- epilogue: transpose via LDS (wave-private region), coalesced stores ----
    float* eb = shm + qw * 2048;   // [32 q][33 d-pad] floats
#pragma unroll
    for (int dt = 0; dt < 2; ++dt) {
#pragma unroll
      for (int i = 0; i < 16; ++i)
        eb[li * 33 + ((i & 3) + 8 * (i >> 2) + 4 * hi)] = acc[dt][i];
      __asm__ volatile("" ::: "memory");
#pragma unroll
      for (int it = 0; it < 16; ++it) {
        int q = it * 2 + hi;
        float v = eb[q * 33 + li];
        out[(size_t)(q0 + q) * 1024 + h * 64 + dt * 32 + li] = v;
      }
      __asm__ volatile("" ::: "memory");
    }
  }
}

extern "C" void kernel_launch(void* const* d_in, const int* in_sizes, int n_in,
                              void* d_out, int out_size, void* d_ws, size_t ws_size,
                              hipStream_t stream) {
  const float* x  = (const float*)d_in[0];
  const float* wq = (const float*)d_in[1];
  const float* wk = (const float*)d_in[2];
  const float* wv = (const float*)d_in[3];
  float* out = (float*)d_out;
  char* ws = (char*)d_ws;

  unsigned short* qbf  = (unsigned short*)(ws);
  unsigned short* Kswz = (unsigned short*)(ws + ((size_t)8 << 20));
  unsigned short* Vswz = (unsigned short*)(ws + ((size_t)16 << 20));
  unsigned short* xbf  = (unsigned short*)(ws + ((size_t)24 << 20));
  unsigned short* wbf  = (unsigned short*)(ws + ((size_t)32 << 20));
  float2* ctst = (float2*)(ws + ((size_t)38 << 20));

  k_prep<<<dim3(7680), dim3(256), 0, stream>>>(x, wq, wk, wv, xbf, wbf, ctst);
  k_gemm<<<dim3(24, 32), dim3(256), 0, stream>>>(xbf, wbf, ctst, qbf, Kswz, Vswz);
  k_attn<<<dim3(512), dim3(512), 0, stream>>>(qbf, Kswz, Vswz, out);
}

// Round 23
// 153.733 us; speedup vs baseline: 1.0064x; 1.0064x over previous
//
#include <hip/hip_runtime.h>
#include <stdint.h>

// RoPE attention, MI355X. S=4096, HID=1024, 16 heads x 64.
// R23 = R21 gemm (cheap row-major kbf + transposed vT epilogue, 40.6us) +
// NEW k_swz re-layout pass (kbf/vT -> pre-swizzled Kswz/Vswz, coalesced, ~6us)
// + R22 attn verbatim (gll16 staging from pre-swizzled global, 94us).
// Decouples the two proven wins that conflicted inside one gemm epilogue.
// ws: qbf 8 | kbf 8 | vT 8 | xbf 8 (->Kswz) | wbf 6 + ctst (->Vswz) | 40MB total

#define SEQLEN 4096
#define NHEAD 16
#define HDIM 64

typedef __bf16 bf16x8 __attribute__((ext_vector_type(8)));
typedef float f32x4 __attribute__((ext_vector_type(4)));
typedef float f32x16 __attribute__((ext_vector_type(16)));

__device__ __forceinline__ unsigned short f2bf(float f) {
  union { float f; unsigned int u; } v; v.f = f;
  unsigned int r = v.u + 0x7FFFu + ((v.u >> 16) & 1u);
  return (unsigned short)(r >> 16);
}
__device__ __forceinline__ unsigned int pkc(float lo, float hi) {
  union { __bf16 b[2]; unsigned int u; } z;
  z.b[0] = (__bf16)lo; z.b[1] = (__bf16)hi;
  return z.u;
}
__device__ __forceinline__ bf16x8 as_bf(uint4 v) { return __builtin_bit_cast(bf16x8, v); }
__device__ __forceinline__ f32x4 mfma16(bf16x8 a, bf16x8 b, f32x4 c) {
  return __builtin_amdgcn_mfma_f32_16x16x32_bf16(a, b, c, 0, 0, 0);
}
__device__ __forceinline__ f32x16 mfma32(bf16x8 a, bf16x8 b, f32x16 c) {
  return __builtin_amdgcn_mfma_f32_32x32x16_bf16(a, b, c, 0, 0, 0);
}
__device__ __forceinline__ void gll16(const void* g, void* l) {
  __builtin_amdgcn_global_load_lds(
      (const __attribute__((address_space(1))) void*)g,
      (__attribute__((address_space(3))) void*)l, 16, 0, 0);
}

// ---------------- prep: fp32->bf16 convert (x, wq|wk|wv) + RoPE float2 table ----
__global__ __launch_bounds__(256) void k_prep(
    const float* __restrict__ x, const float* __restrict__ wq,
    const float* __restrict__ wk, const float* __restrict__ wv,
    unsigned short* __restrict__ xbf, unsigned short* __restrict__ wbf,
    float2* __restrict__ ctst) {
  const int NX = SEQLEN * 1024 / 4;         // 1048576 float4s
  const int NW = 1024 * 1024 / 4;           // 262144 (pow2)
  if (blockIdx.x < 7168) {
    int i = blockIdx.x * 256 + threadIdx.x;
    float4 v;
    unsigned short* dst;
    int di;
    if (i < NX) {
      v = ((const float4*)x)[i]; dst = xbf; di = i;
    } else {
      int j = i - NX;
      const float4* src = (const float4*)((j < NW) ? wq : (j < 2 * NW) ? wk : wv);
      v = src[j & (NW - 1)];
      dst = wbf; di = j;
    }
    ushort4 o; o.x = f2bf(v.x); o.y = f2bf(v.y); o.z = f2bf(v.z); o.w = f2bf(v.w);
    ((ushort4*)dst)[di] = o;
  } else {
    int i = (blockIdx.x - 7168) * 256 + threadIdx.x;   // 4096*32 entries
    int s = i >> 5, j = i & 31;
    double inv = exp(-(double)j * 0.28782313662425572);  // ln(10000)/32
    double a = (double)s * inv;
    float2 cs; cs.x = (float)cos(a); cs.y = (float)sin(a);
    ctst[i] = cs;
  }
}

// ---------------- QKV GEMM (R21 verbatim: gll16 staging + cheap epilogue) ----------
__global__ __launch_bounds__(256) void k_gemm(
    const unsigned short* __restrict__ xbf, const unsigned short* __restrict__ wbf,
    const float2* __restrict__ ctst,
    unsigned short* __restrict__ qbf, unsigned short* __restrict__ kbf,
    unsigned short* __restrict__ vT) {
  __shared__ __align__(16) unsigned short As[2][128 * 32];  // 8KB per buffer
  __shared__ __align__(16) unsigned short Bs[2][128 * 32];
  const int t = threadIdx.x;
  const int bn = blockIdx.x, bm = blockIdx.y;
  const int lane = t & 63, wave = t >> 6;
  const int r = lane & 15, g = lane >> 4;
  const int wm = wave >> 1, wn = wave & 1;

  const int c0 = 2 * wave, c1 = 2 * wave + 1;
  const int srowA = lane >> 2, sb = (lane & 3) * 16;
  const char* gA0 = (const char*)xbf + (size_t)(bm * 128 + 16 * c0 + srowA) * 2048 + sb;
  const char* gA1 = (const char*)xbf + (size_t)(bm * 128 + 16 * c1 + srowA) * 2048 + sb;
  const char* gB0 = (const char*)wbf + (size_t)(bn * 128 + 16 * c0 + srowA) * 2048 + sb;
  const char* gB1 = (const char*)wbf + (size_t)(bn * 128 + 16 * c1 + srowA) * 2048 + sb;

  gll16(gA0, (char*)As[0] + c0 * 1024);
  gll16(gA1, (char*)As[0] + c1 * 1024);
  gll16(gB0, (char*)Bs[0] + c0 * 1024);
  gll16(gB1, (char*)Bs[0] + c1 * 1024);
  gA0 += 64; gA1 += 64; gB0 += 64; gB1 += 64;

  f32x4 zero4 = {0.f, 0.f, 0.f, 0.f};
  f32x4 acc[4][4];
#pragma unroll
  for (int m = 0; m < 4; ++m)
#pragma unroll
    for (int n = 0; n < 4; ++n) acc[m][n] = zero4;

  for (int kk = 0; kk < 32; ++kk) {
    __syncthreads();
    if (kk < 31) {
      char* Ad = (char*)As[(kk + 1) & 1];
      char* Bd = (char*)Bs[(kk + 1) & 1];
      gll16(gA0, Ad + c0 * 1024);
      gll16(gA1, Ad + c1 * 1024);
      gll16(gB0, Bd + c0 * 1024);
      gll16(gB1, Bd + c1 * 1024);
      gA0 += 64; gA1 += 64; gB0 += 64; gB1 += 64;
    }
    const char* Ac = (const char*)As[kk & 1];
    const char* Bc = (const char*)Bs[kk & 1];
    bf16x8 af[4], bfr[4];
#pragma unroll
    for (int m = 0; m < 4; ++m)
      af[m] = as_bf(*(const uint4*)(Ac + (wm * 64 + m * 16 + r) * 64 + g * 16));
#pragma unroll
    for (int n = 0; n < 4; ++n)
      bfr[n] = as_bf(*(const uint4*)(Bc + (wn * 64 + n * 16 + r) * 64 + g * 16));
#pragma unroll
    for (int m = 0; m < 4; ++m)
#pragma unroll
      for (int n = 0; n < 4; ++n)
        acc[m][n] = mfma16(af[m], bfr[n], acc[m][n]);
  }

  const int matid = bn >> 3;  // 0=q, 1=k, 2=v
#pragma unroll
  for (int m = 0; m < 4; ++m) {
    const int row0 = bm * 128 + wm * 64 + m * 16 + 4 * g;
#pragma unroll
    for (int n = 0; n < 4; ++n) {
      const int col = bn * 128 + wn * 64 + n * 16 + r;
      const int d = col & 63;
      const int hh = (col >> 6) & 15;
      if (matid < 2) {
        const int jdx = (col >> 1) & 31;
        const float sgn = (col & 1) ? 1.0f : -1.0f;
        unsigned short* dst = (matid == 0) ? qbf : kbf;
        const float qs = (matid == 0) ? 0.18033688011112042f : 1.0f;
#pragma unroll
        for (int j = 0; j < 4; ++j) {
          float v = acc[m][n][j];
          float p = __shfl_xor(v, 1);  // RoPE pair partner (col^1)
          int srow = row0 + j;
          float2 cs = ctst[srow * 32 + jdx];
          float o = (v * cs.x + p * cs.y * sgn) * qs;
          dst[(size_t)srow * 1024 + (hh * 64 + d)] = f2bf(o);
        }
      } else {
        // V stored transposed: vT[h][d][s]
        ushort4 o;
        o.x = f2bf(acc[m][n][0]); o.y = f2bf(acc[m][n][1]);
        o.z = f2bf(acc[m][n][2]); o.w = f2bf(acc[m][n][3]);
        *(ushort4*)&vT[((size_t)(hh * 64 + d)) * SEQLEN + row0] = o;
      }
    }
  }
}

// ---------------- swizzle re-layout: kbf/vT -> Kswz/Vswz (coalesced) ----------------
// K: Kswz[h][key][s*8] = kbf 8B at row key, orig slot os = s ^ (key&15).
// V: Vswz[h][kt][vr][s*8] = vT 8B (4 keys) at d = (os>>3)*32+vr, key4 = kt*32+(os&7)*4,
//    os = s ^ (vr&15).
__global__ __launch_bounds__(256) void k_swz(
    const unsigned short* __restrict__ kbf, const unsigned short* __restrict__ vT,
    unsigned long long* __restrict__ Kswz, unsigned long long* __restrict__ Vswz) {
  const int e = (blockIdx.x & 4095) * 256 + threadIdx.x;   // 1M granules each side
  if (blockIdx.x < 4096) {
    const int s = e & 15, key = (e >> 4) & 4095, h = e >> 16;
    const int os = s ^ (key & 15);
    unsigned long long v = *(const unsigned long long*)
        ((const char*)kbf + (size_t)key * 2048 + h * 128 + os * 8);
    Kswz[((size_t)h << 16) | ((size_t)key << 4) | s] = v;
  } else {
    const int s = e & 15, vr = (e >> 4) & 31, kt = (e >> 9) & 127, h = e >> 16;
    const int os = s ^ (vr & 15);
    const int d = (os >> 3) * 32 + vr;
    const int key4 = kt * 32 + (os & 7) * 4;
    unsigned long long v = *(const unsigned long long*)
        ((const char*)vT + ((size_t)(h * 64 + d)) * 8192 + key4 * 2);
    Vswz[((size_t)h << 16) | ((size_t)kt << 9) | ((size_t)vr << 4) | s] = v;
  }
}

// ---------------- Flash attention (R22 verbatim: gll16 from pre-swizzled global) ----
__global__ __launch_bounds__(512) void k_attn(
    const unsigned short* __restrict__ qbf, const unsigned short* __restrict__ Kswz,
    const unsigned short* __restrict__ Vswz, float* __restrict__ out) {
  __shared__ __align__(16) char smem[33280];
  const int t = threadIdx.x;
  // XCD swizzle: 512 blocks, 8 XCDs, 64 blocks/XCD -> 2 heads per XCD
  const int b = blockIdx.x;
  const int work = (b & 7) * 64 + (b >> 3);
  const int h = work >> 5;
  const int qb = work & 31;
  const int lane = t & 63, wave = t >> 6;
  const int qw = wave & 3, hf = wave >> 2;
  const int li = lane & 31, hi = lane >> 5;
  const int q0 = qb * 128 + qw * 32;
  const int HB = hf * 16384;

  bf16x8 qf[4];
#pragma unroll
  for (int c = 0; c < 4; ++c)
    qf[c] = as_bf(*(const uint4*)((const char*)qbf +
              (size_t)(q0 + li) * 2048 + h * 128 + c * 32 + hi * 16));

  f32x16 z16 = {0.f};
  f32x16 acc[2];
  acc[0] = z16; acc[1] = z16;
  float l4[4] = {0.f, 0.f, 0.f, 0.f};

  const int mmK = (li & 15) ^ (hi << 1);
  int kra[4];
#pragma unroll
  for (int c = 0; c < 4; ++c)
    kra[c] = HB + li * 128 + ((((4 * c) ^ mmK)) << 3);
  const int mmV = (li & 15) ^ hi;
  int vra[2][2];
#pragma unroll
  for (int dt = 0; dt < 2; ++dt)
#pragma unroll
    for (int kc = 0; kc < 2; ++kc)
      vra[dt][kc] = HB + 8192 + li * 128 + ((((dt * 8 + 4 * kc) ^ mmV)) << 3);

  const char* pK = (const char*)Kswz + (size_t)h * 524288 + (size_t)hf * 262144 +
                   (size_t)qw * 1024 + (size_t)lane * 16;
  const char* pV = (const char*)Vswz + (size_t)h * 524288 + (size_t)hf * 262144 +
                   (size_t)qw * 1024 + (size_t)lane * 16;
  char* dK = smem + HB + qw * 1024;
  char* dV = smem + HB + 8192 + qw * 1024;

  gll16(pK, dK);
  gll16(pV, dV);
  pK += 4096; pV += 4096;

  for (int j = 0; j < 64; ++j) {
    __syncthreads();
    if (j < 63) {
      const int NB = ((j + 1) & 1) * 4096;
      gll16(pK, dK + NB);
      gll16(pV, dV + NB);
      pK += 4096; pV += 4096;
    }
    const int JB = (j & 1) * 4096;

    f32x16 sT = z16;
    __builtin_amdgcn_s_setprio(1);
#pragma unroll
    for (int c = 0; c < 4; ++c) {
      uint2 a0 = *(const uint2*)(smem + (kra[c] + JB));
      uint2 a1 = *(const uint2*)(smem + ((kra[c] ^ 8) + JB));
      uint4 ku; ku.x = a0.x; ku.y = a0.y; ku.z = a1.x; ku.w = a1.y;
      sT = mfma32(as_bf(ku), qf[c], sT);
    }
    __builtin_amdgcn_s_setprio(0);

    bf16x8 vf[2][2];
#pragma unroll
    for (int dt = 0; dt < 2; ++dt)
#pragma unroll
      for (int kc = 0; kc < 2; ++kc) {
        uint2 lo = *(const uint2*)(smem + (vra[dt][kc] + JB));
        uint2 hi2 = *(const uint2*)(smem + ((vra[dt][kc] ^ 16) + JB));
        uint4 vv; vv.x = lo.x; vv.y = lo.y; vv.z = hi2.x; vv.w = hi2.y;
        vf[dt][kc] = as_bf(vv);
      }

#pragma unroll
    for (int i = 0; i < 16; ++i) sT[i] = __builtin_amdgcn_exp2f(sT[i]);

#pragma unroll
    for (int i = 0; i < 4; ++i)
      l4[i] += (sT[i] + sT[i + 4]) + (sT[i + 8] + sT[i + 12]);

    bf16x8 pfr[2];
#pragma unroll
    for (int kc = 0; kc < 2; ++kc) {
      const int bix = kc * 8;
      uint4 bw;
      bw.x = pkc(sT[bix + 0], sT[bix + 1]);
      bw.y = pkc(sT[bix + 2], sT[bix + 3]);
      bw.z = pkc(sT[bix + 4], sT[bix + 5]);
      bw.w = pkc(sT[bix + 6], sT[bix + 7]);
      pfr[kc] = as_bf(bw);
    }
    __builtin_amdgcn_s_setprio(1);
#pragma unroll
    for (int kc = 0; kc < 2; ++kc) {
      acc[0] = mfma32(vf[0][kc], pfr[kc], acc[0]);
      acc[1] = mfma32(vf[1][kc], pfr[kc], acc[1]);
    }
    __builtin_amdgcn_s_setprio(0);
  }

  float lrun = (l4[0] + l4[1]) + (l4[2] + l4[3]);
  float lhalf = lrun + __shfl_xor(lrun, 32);

  __syncthreads();
  float* shm = (float*)smem;
  if (hf == 1) {
    float* ab = shm + qw * 2048;   // [64 d][32 q]
#pragma unroll
    for (int dt = 0; dt < 2; ++dt)
#pragma unroll
      for (int i = 0; i < 16; ++i) {
        int d = (i & 3) + 8 * (i >> 2) + 4 * hi + 32 * dt;
        ab[d * 32 + li] = acc[dt][i];
      }
    if (hi == 0) shm[8192 + qw * 32 + li] = lhalf;
  }
  __syncthreads();
  if (hf == 0) {
    float* ab = shm + qw * 2048;
    float l1 = shm[8192 + qw * 32 + li];
    float linv = 1.0f / (lhalf + l1);
#pragma unroll
    for (int dt = 0; dt < 2; ++dt)
#pragma unroll
      for (int i = 0; i < 16; ++i) {
        int d = (i & 3) + 8 * (i >> 2) + 4 * hi + 32 * dt;
        acc[dt][i] = (acc[dt][i] + ab[d * 32 + li]) * linv;
      }
    __asm__ volatile("" ::: "memory");

    float* eb = shm + qw * 2048;   // [32 q][33 d-pad] floats
#pragma unroll
    for (int dt = 0; dt < 2; ++dt) {
#pragma unroll
      for (int i = 0; i < 16; ++i)
        eb[li * 33 + ((i & 3) + 8 * (i >> 2) + 4 * hi)] = acc[dt][i];
      __asm__ volatile("" ::: "memory");
#pragma unroll
      for (int it = 0; it < 16; ++it) {
        int q = it * 2 + hi;
        float v = eb[q * 33 + li];
        out[(size_t)(q0 + q) * 1024 + h * 64 + dt * 32 + li] = v;
      }
      __asm__ volatile("" ::: "memory");
    }
  }
}

extern "C" void kernel_launch(void* const* d_in, const int* in_sizes, int n_in,
                              void* d_out, int out_size, void* d_ws, size_t ws_size,
                              hipStream_t stream) {
  const float* x  = (const float*)d_in[0];
  const float* wq = (const float*)d_in[1];
  const float* wk = (const float*)d_in[2];
  const float* wv = (const float*)d_in[3];
  float* out = (float*)d_out;
  char* ws = (char*)d_ws;

  unsigned short* qbf = (unsigned short*)(ws);
  unsigned short* kbf = (unsigned short*)(ws + ((size_t)8 << 20));
  unsigned short* vT  = (unsigned short*)(ws + ((size_t)16 << 20));
  unsigned short* xbf = (unsigned short*)(ws + ((size_t)24 << 20));
  unsigned short* wbf = (unsigned short*)(ws + ((size_t)32 << 20));
  float2* ctst = (float2*)(ws + ((size_t)38 << 20));
  // after gemm, xbf/wbf/ctst are dead: reuse for the swizzled images
  unsigned long long* Kswz = (unsigned long long*)(ws + ((size_t)24 << 20));
  unsigned long long* Vswz = (unsigned long long*)(ws + ((size_t)32 << 20));

  k_prep<<<dim3(7680), dim3(256), 0, stream>>>(x, wq, wk, wv, xbf, wbf, ctst);
  k_gemm<<<dim3(24, 32), dim3(256), 0, stream>>>(xbf, wbf, ctst, qbf, kbf, vT);
  k_swz<<<dim3(8192), dim3(256), 0, stream>>>(kbf, vT, Kswz, Vswz);
  k_attn<<<dim3(512), dim3(512), 0, stream>>>(qbf, (const unsigned short*)Kswz,
                                              (const unsigned short*)Vswz, out);
}

// Round 24
// 144.872 us; speedup vs baseline: 1.0679x; 1.0612x over previous
//
#include <hip/hip_runtime.h>
#include <stdint.h>

// RoPE attention, MI355X. S=4096, HID=1024, 16 heads x 64.
// R24 = R21 gemm (cheap row-major kbf + transposed vT, 47.6us non-attn) + attn
// staging via gll16 with PER-LANE PRE-SWIZZLED GLOBAL SOURCE ADDRESSES straight
// from kbf/vT (rule #21 done right: no intermediate swizzled buffer, no k_swz).
// Swizzle re-derived at 16B granularity (granule ^= row&7) so each gll16 lane
// granule is contiguous in the source; K frag read becomes a single b128.
// ws layout: qbf 8MB | kbf 8MB | vT 8MB | xbf 8MB | wbf 6MB | ctst 1MB

#define SEQLEN 4096
#define NHEAD 16
#define HDIM 64

typedef __bf16 bf16x8 __attribute__((ext_vector_type(8)));
typedef float f32x4 __attribute__((ext_vector_type(4)));
typedef float f32x16 __attribute__((ext_vector_type(16)));

__device__ __forceinline__ unsigned short f2bf(float f) {
  union { float f; unsigned int u; } v; v.f = f;
  unsigned int r = v.u + 0x7FFFu + ((v.u >> 16) & 1u);
  return (unsigned short)(r >> 16);
}
__device__ __forceinline__ unsigned int pkc(float lo, float hi) {
  union { __bf16 b[2]; unsigned int u; } z;
  z.b[0] = (__bf16)lo; z.b[1] = (__bf16)hi;
  return z.u;
}
__device__ __forceinline__ bf16x8 as_bf(uint4 v) { return __builtin_bit_cast(bf16x8, v); }
__device__ __forceinline__ f32x4 mfma16(bf16x8 a, bf16x8 b, f32x4 c) {
  return __builtin_amdgcn_mfma_f32_16x16x32_bf16(a, b, c, 0, 0, 0);
}
__device__ __forceinline__ f32x16 mfma32(bf16x8 a, bf16x8 b, f32x16 c) {
  return __builtin_amdgcn_mfma_f32_32x32x16_bf16(a, b, c, 0, 0, 0);
}
__device__ __forceinline__ void gll16(const void* g, void* l) {
  __builtin_amdgcn_global_load_lds(
      (const __attribute__((address_space(1))) void*)g,
      (__attribute__((address_space(3))) void*)l, 16, 0, 0);
}

// ---------------- prep: fp32->bf16 convert (x, wq|wk|wv) + RoPE float2 table ----
__global__ __launch_bounds__(256) void k_prep(
    const float* __restrict__ x, const float* __restrict__ wq,
    const float* __restrict__ wk, const float* __restrict__ wv,
    unsigned short* __restrict__ xbf, unsigned short* __restrict__ wbf,
    float2* __restrict__ ctst) {
  const int NX = SEQLEN * 1024 / 4;         // 1048576 float4s
  const int NW = 1024 * 1024 / 4;           // 262144 (pow2)
  if (blockIdx.x < 7168) {
    int i = blockIdx.x * 256 + threadIdx.x;
    float4 v;
    unsigned short* dst;
    int di;
    if (i < NX) {
      v = ((const float4*)x)[i]; dst = xbf; di = i;
    } else {
      int j = i - NX;
      const float4* src = (const float4*)((j < NW) ? wq : (j < 2 * NW) ? wk : wv);
      v = src[j & (NW - 1)];
      dst = wbf; di = j;
    }
    ushort4 o; o.x = f2bf(v.x); o.y = f2bf(v.y); o.z = f2bf(v.z); o.w = f2bf(v.w);
    ((ushort4*)dst)[di] = o;
  } else {
    int i = (blockIdx.x - 7168) * 256 + threadIdx.x;   // 4096*32 entries
    int s = i >> 5, j = i & 31;
    double inv = exp(-(double)j * 0.28782313662425572);  // ln(10000)/32
    double a = (double)s * inv;
    float2 cs; cs.x = (float)cos(a); cs.y = (float)sin(a);
    ctst[i] = cs;
  }
}

// ---------------- QKV GEMM (R21 verbatim: gll16 staging + cheap epilogue) ----------
__global__ __launch_bounds__(256) void k_gemm(
    const unsigned short* __restrict__ xbf, const unsigned short* __restrict__ wbf,
    const float2* __restrict__ ctst,
    unsigned short* __restrict__ qbf, unsigned short* __restrict__ kbf,
    unsigned short* __restrict__ vT) {
  __shared__ __align__(16) unsigned short As[2][128 * 32];  // 8KB per buffer
  __shared__ __align__(16) unsigned short Bs[2][128 * 32];
  const int t = threadIdx.x;
  const int bn = blockIdx.x, bm = blockIdx.y;
  const int lane = t & 63, wave = t >> 6;
  const int r = lane & 15, g = lane >> 4;
  const int wm = wave >> 1, wn = wave & 1;

  const int c0 = 2 * wave, c1 = 2 * wave + 1;
  const int srowA = lane >> 2, sb = (lane & 3) * 16;
  const char* gA0 = (const char*)xbf + (size_t)(bm * 128 + 16 * c0 + srowA) * 2048 + sb;
  const char* gA1 = (const char*)xbf + (size_t)(bm * 128 + 16 * c1 + srowA) * 2048 + sb;
  const char* gB0 = (const char*)wbf + (size_t)(bn * 128 + 16 * c0 + srowA) * 2048 + sb;
  const char* gB1 = (const char*)wbf + (size_t)(bn * 128 + 16 * c1 + srowA) * 2048 + sb;

  gll16(gA0, (char*)As[0] + c0 * 1024);
  gll16(gA1, (char*)As[0] + c1 * 1024);
  gll16(gB0, (char*)Bs[0] + c0 * 1024);
  gll16(gB1, (char*)Bs[0] + c1 * 1024);
  gA0 += 64; gA1 += 64; gB0 += 64; gB1 += 64;

  f32x4 zero4 = {0.f, 0.f, 0.f, 0.f};
  f32x4 acc[4][4];
#pragma unroll
  for (int m = 0; m < 4; ++m)
#pragma unroll
    for (int n = 0; n < 4; ++n) acc[m][n] = zero4;

  for (int kk = 0; kk < 32; ++kk) {
    __syncthreads();
    if (kk < 31) {
      char* Ad = (char*)As[(kk + 1) & 1];
      char* Bd = (char*)Bs[(kk + 1) & 1];
      gll16(gA0, Ad + c0 * 1024);
      gll16(gA1, Ad + c1 * 1024);
      gll16(gB0, Bd + c0 * 1024);
      gll16(gB1, Bd + c1 * 1024);
      gA0 += 64; gA1 += 64; gB0 += 64; gB1 += 64;
    }
    const char* Ac = (const char*)As[kk & 1];
    const char* Bc = (const char*)Bs[kk & 1];
    bf16x8 af[4], bfr[4];
#pragma unroll
    for (int m = 0; m < 4; ++m)
      af[m] = as_bf(*(const uint4*)(Ac + (wm * 64 + m * 16 + r) * 64 + g * 16));
#pragma unroll
    for (int n = 0; n < 4; ++n)
      bfr[n] = as_bf(*(const uint4*)(Bc + (wn * 64 + n * 16 + r) * 64 + g * 16));
#pragma unroll
    for (int m = 0; m < 4; ++m)
#pragma unroll
      for (int n = 0; n < 4; ++n)
        acc[m][n] = mfma16(af[m], bfr[n], acc[m][n]);
  }

  const int matid = bn >> 3;  // 0=q, 1=k, 2=v
#pragma unroll
  for (int m = 0; m < 4; ++m) {
    const int row0 = bm * 128 + wm * 64 + m * 16 + 4 * g;
#pragma unroll
    for (int n = 0; n < 4; ++n) {
      const int col = bn * 128 + wn * 64 + n * 16 + r;
      const int d = col & 63;
      const int hh = (col >> 6) & 15;
      if (matid < 2) {
        const int jdx = (col >> 1) & 31;
        const float sgn = (col & 1) ? 1.0f : -1.0f;
        unsigned short* dst = (matid == 0) ? qbf : kbf;
        const float qs = (matid == 0) ? 0.18033688011112042f : 1.0f;
#pragma unroll
        for (int j = 0; j < 4; ++j) {
          float v = acc[m][n][j];
          float p = __shfl_xor(v, 1);  // RoPE pair partner (col^1)
          int srow = row0 + j;
          float2 cs = ctst[srow * 32 + jdx];
          float o = (v * cs.x + p * cs.y * sgn) * qs;
          dst[(size_t)srow * 1024 + (hh * 64 + d)] = f2bf(o);
        }
      } else {
        // V stored transposed: vT[h][d][s]
        ushort4 o;
        o.x = f2bf(acc[m][n][0]); o.y = f2bf(acc[m][n][1]);
        o.z = f2bf(acc[m][n][2]); o.w = f2bf(acc[m][n][3]);
        *(ushort4*)&vT[((size_t)(hh * 64 + d)) * SEQLEN + row0] = o;
      }
    }
  }
}

// ---------------- Flash attention (KVBLK=32; gll16 staging with per-lane
//                  swizzled global sources; 16B-granule swizzle: g ^= row&7) ----
__global__ __launch_bounds__(512) void k_attn(
    const unsigned short* __restrict__ qbf, const unsigned short* __restrict__ kbf,
    const unsigned short* __restrict__ vT, float* __restrict__ out) {
  __shared__ __align__(16) char smem[33280];
  const int t = threadIdx.x;
  // XCD swizzle: 512 blocks, 8 XCDs, 64 blocks/XCD -> 2 heads per XCD
  const int b = blockIdx.x;
  const int work = (b & 7) * 64 + (b >> 3);
  const int h = work >> 5;
  const int qb = work & 31;
  const int lane = t & 63, wave = t >> 6;
  const int qw = wave & 3, hf = wave >> 2;
  const int li = lane & 31, hi = lane >> 5;
  const int q0 = qb * 128 + qw * 32;
  const int HB = hf * 16384;

  // Q fragments: lane holds q = q0+li, d = c*16 + hi*8 + j. Pre-scaled.
  bf16x8 qf[4];
#pragma unroll
  for (int c = 0; c < 4; ++c)
    qf[c] = as_bf(*(const uint4*)((const char*)qbf +
              (size_t)(q0 + li) * 2048 + h * 128 + c * 32 + hi * 16));

  f32x16 z16 = {0.f};
  f32x16 acc[2];
  acc[0] = z16; acc[1] = z16;
  float l4[4] = {0.f, 0.f, 0.f, 0.f};

  // ---- LDS read addresses (16B-granule swizzle) ----
  // K: lane wants orig granule 2c+hi of row li -> swz granule (2c+hi)^(li&7); b128.
  int kra[4];
#pragma unroll
  for (int c = 0; c < 4; ++c)
    kra[c] = HB + li * 128 + (((2 * c + hi) ^ (li & 7)) << 4);
  // V: orig 8B slots (dt*8+4kc+hi, +2) -> granules (4dt+2kc)^(li&7), partner ^1;
  //    inner 8B = hi. b64 pair at vra and vra^16.
  int vra[2][2];
#pragma unroll
  for (int dt = 0; dt < 2; ++dt)
#pragma unroll
    for (int kc = 0; kc < 2; ++kc)
      vra[dt][kc] = HB + 8192 + li * 128 + (((4 * dt + 2 * kc) ^ (li & 7)) << 4) + hi * 8;

  // ---- gll16 staging: wave qw stages rows qw*8..+7 of K and V tiles ----
  const int srow = qw * 8 + (lane >> 3);       // LDS row this lane fills
  const int gg = lane & 7;                     // swizzled 16B granule
  const int og = gg ^ (srow & 7);              // original granule (srow&7 == lane>>3)
  // K source: key = hf*2048 + kt*32 + srow, bytes h*128 + og*16
  const char* pK = (const char*)kbf + h * 128 +
                   (size_t)(hf * 2048 + srow) * 2048 + og * 16;
  // V source: d = (og>>2)*32 + srow, keys hf*2048 + kt*32 + (og&3)*8 (16B = 8 keys)
  const char* pV = (const char*)vT + (size_t)(h * 64 + (og >> 2) * 32 + srow) * 8192 +
                   hf * 4096 + (og & 3) * 16;
  char* dK = smem + HB + qw * 1024;            // wave-uniform LDS dests
  char* dV = smem + HB + 8192 + qw * 1024;

  // prologue: tile 0 -> buffer 0
  gll16(pK, dK);
  gll16(pV, dV);
  pK += 32 * 2048; pV += 64;

  for (int j = 0; j < 64; ++j) {
    __syncthreads();   // tile-j staging complete; prior reads drained
    if (j < 63) {
      const int NB = ((j + 1) & 1) * 4096;
      gll16(pK, dK + NB);
      gll16(pV, dV + NB);
      pK += 32 * 2048; pV += 64;
    }
    const int JB = (j & 1) * 4096;

    // ---- QK^T: S^T[key][q], one 32-key subtile ----
    f32x16 sT = z16;
    __builtin_amdgcn_s_setprio(1);
#pragma unroll
    for (int c = 0; c < 4; ++c) {
      bf16x8 kf = as_bf(*(const uint4*)(smem + (kra[c] + JB)));
      sT = mfma32(kf, qf[c], sT);
    }
    __builtin_amdgcn_s_setprio(0);

    // ---- V A-frags (sigma order) ----
    bf16x8 vf[2][2];
#pragma unroll
    for (int dt = 0; dt < 2; ++dt)
#pragma unroll
      for (int kc = 0; kc < 2; ++kc) {
        uint2 lo = *(const uint2*)(smem + (vra[dt][kc] + JB));
        uint2 hi2 = *(const uint2*)(smem + ((vra[dt][kc] ^ 16) + JB));
        uint4 vv; vv.x = lo.x; vv.y = lo.y; vv.z = hi2.x; vv.w = hi2.y;
        vf[dt][kc] = as_bf(vv);
      }

    // ---- p = exp2(raw score); bounded, no max needed ----
#pragma unroll
    for (int i = 0; i < 16; ++i) sT[i] = __builtin_amdgcn_exp2f(sT[i]);

    // ---- denominator partials ----
#pragma unroll
    for (int i = 0; i < 4; ++i)
      l4[i] += (sT[i] + sT[i + 4]) + (sT[i + 8] + sT[i + 12]);

    // ---- pack P B-frags, then 4-MFMA PV cluster ----
    bf16x8 pfr[2];
#pragma unroll
    for (int kc = 0; kc < 2; ++kc) {
      const int bix = kc * 8;
      uint4 bw;
      bw.x = pkc(sT[bix + 0], sT[bix + 1]);
      bw.y = pkc(sT[bix + 2], sT[bix + 3]);
      bw.z = pkc(sT[bix + 4], sT[bix + 5]);
      bw.w = pkc(sT[bix + 6], sT[bix + 7]);
      pfr[kc] = as_bf(bw);
    }
    __builtin_amdgcn_s_setprio(1);
#pragma unroll
    for (int kc = 0; kc < 2; ++kc) {
      acc[0] = mfma32(vf[0][kc], pfr[kc], acc[0]);
      acc[1] = mfma32(vf[1][kc], pfr[kc], acc[1]);
    }
    __builtin_amdgcn_s_setprio(0);
  }

  float lrun = (l4[0] + l4[1]) + (l4[2] + l4[3]);
  float lhalf = lrun + __shfl_xor(lrun, 32);

  // ---- flash-combine of the two KV halves via LDS (plain add; no max) ----
  __syncthreads();
  float* shm = (float*)smem;
  if (hf == 1) {
    float* ab = shm + qw * 2048;   // [64 d][32 q]
#pragma unroll
    for (int dt = 0; dt < 2; ++dt)
#pragma unroll
      for (int i = 0; i < 16; ++i) {
        int d = (i & 3) + 8 * (i >> 2) + 4 * hi + 32 * dt;
        ab[d * 32 + li] = acc[dt][i];
      }
    if (hi == 0) shm[8192 + qw * 32 + li] = lhalf;
  }
  __syncthreads();
  if (hf == 0) {
    float* ab = shm + qw * 2048;
    float l1 = shm[8192 + qw * 32 + li];
    float linv = 1.0f / (lhalf + l1);
#pragma unroll
    for (int dt = 0; dt < 2; ++dt)
#pragma unroll
      for (int i = 0; i < 16; ++i) {
        int d = (i & 3) + 8 * (i >> 2) + 4 * hi + 32 * dt;
        acc[dt][i] = (acc[dt][i] + ab[d * 32 + li]) * linv;
      }
    __asm__ volatile("" ::: "memory");

    // ---- epilogue: transpose via LDS (wave-private region), coalesced stores ----
    float* eb = shm + qw * 2048;   // [32 q][33 d-pad] floats
#pragma unroll
    for (int dt = 0; dt < 2; ++dt) {
#pragma unroll
      for (int i = 0; i < 16; ++i)
        eb[li * 33 + ((i & 3) + 8 * (i >> 2) + 4 * hi)] = acc[dt][i];
      __asm__ volatile("" ::: "memory");
#pragma unroll
      for (int it = 0; it < 16; ++it) {
        int q = it * 2 + hi;
        float v = eb[q * 33 + li];
        out[(size_t)(q0 + q) * 1024 + h * 64 + dt * 32 + li] = v;
      }
      __asm__ volatile("" ::: "memory");
    }
  }
}

extern "C" void kernel_launch(void* const* d_in, const int* in_sizes, int n_in,
                              void* d_out, int out_size, void* d_ws, size_t ws_size,
                              hipStream_t stream) {
  const float* x  = (const float*)d_in[0];
  const float* wq = (const float*)d_in[1];
  const float* wk = (const float*)d_in[2];
  const float* wv = (const float*)d_in[3];
  float* out = (float*)d_out;
  char* ws = (char*)d_ws;

  unsigned short* qbf = (unsigned short*)(ws);
  unsigned short* kbf = (unsigned short*)(ws + ((size_t)8 << 20));
  unsigned short* vT  = (unsigned short*)(ws + ((size_t)16 << 20));
  unsigned short* xbf = (unsigned short*)(ws + ((size_t)24 << 20));
  unsigned short* wbf = (unsigned short*)(ws + ((size_t)32 << 20));
  float2* ctst = (float2*)(ws + ((size_t)38 << 20));

  k_prep<<<dim3(7680), dim3(256), 0, stream>>>(x, wq, wk, wv, xbf, wbf, ctst);
  k_gemm<<<dim3(24, 32), dim3(256), 0, stream>>>(xbf, wbf, ctst, qbf, kbf, vT);
  k_attn<<<dim3(512), dim3(512), 0, stream>>>(qbf, kbf, vT, out);
}